// Round 18
// baseline (42.830 us; speedup 1.0000x reference)
//
#include <hip/hip_runtime.h>

__device__ __forceinline__ float fexp2(float x) { return __builtin_amdgcn_exp2f(x); }
__device__ __forceinline__ float flog2(float x) { return __builtin_amdgcn_logf(x); }

#define WS1 0.60653065971263342f   // exp(-0.5)
#define WS2 0.36787944117144233f   // exp(-1)

// ---------------- kernel 1: mask plane (uchar per pixel) ----------------
// thread -> 4 masks at (b, h, w0..w0+3)
__global__ __launch_bounds__(256) void mask_kernel(
    const float* __restrict__ orig, const float* __restrict__ smo,
    unsigned char* __restrict__ mask)
{
    const int gid = blockIdx.x * 256 + threadIdx.x;   // 8*512*128 threads
    const int b   = gid >> 16;
    const int rem = gid & 65535;
    const int h   = rem >> 7;
    const int w0  = (rem & 127) << 2;

    const int hp = (h == 511) ? 510 : h + 1;          // reflect
    const int w4 = (w0 + 4 > 511) ? 510 : w0 + 4;     // reflect (w0+4==512 only)

    float eo0=0,eo1=0,eo2=0,eo3=0, es0=0,es1=0,es2=0,es3=0;
    #pragma unroll
    for (int p = 0; p < 6; ++p) {
        const int ch = (p < 3) ? p : p - 3;
        const float* g  = ((p < 3) ? orig : smo) + ((b * 3 + ch) << 18);
        const float* r0 = g + (h  << 9);
        const float* r1 = g + (hp << 9);
        float4 a = *(const float4*)(r0 + w0);
        float  a4 = r0[w4];
        float4 d = *(const float4*)(r1 + w0);
        float t, e0=0,e1=0,e2=0,e3=0;
        t = a.x - d.x; e0 += t*t;  t = a.x - a.y; e0 += t*t;
        t = a.y - d.y; e1 += t*t;  t = a.y - a.z; e1 += t*t;
        t = a.z - d.z; e2 += t*t;  t = a.z - a.w; e2 += t*t;
        t = a.w - d.w; e3 += t*t;  t = a.w - a4;  e3 += t*t;
        if (p < 3) { eo0+=e0; eo1+=e1; eo2+=e2; eo3+=e3; }
        else       { es0+=e0; es1+=e1; es2+=e2; es3+=e3; }
    }
    uchar4 m;
    m.x = (eo0 < 1.f && es0-eo0 > 1.f) ? 1 : 0;
    m.y = (eo1 < 1.f && es1-eo1 > 1.f) ? 1 : 0;
    m.z = (eo2 < 1.f && es2-eo2 > 1.f) ? 1 : 0;
    m.w = (eo3 < 1.f && es3-eo3 > 1.f) ? 1 : 0;
    *(uchar4*)(mask + ((b << 18) | (h << 9) | w0)) = m;
}

// ---------------- kernel 2: pair march (masks read as bytes) ----------------
struct PairP { float ps, sq; };

template<int CI, int CJ>
__device__ __forceinline__ PairP pp(const float (&I)[6][4], const float (&J)[6][4], float wsd)
{
    float d0 = I[0][CI] - J[0][CJ], d1 = I[1][CI] - J[1][CJ], d2 = I[2][CI] - J[2][CJ];
    float sO = fmaf(d0, d0, fmaf(d1, d1, d2 * d2));
    float t0 = fabsf(I[3][CI] - J[3][CJ]) + 1e-8f;
    float t1 = fabsf(I[4][CI] - J[4][CJ]) + 1e-8f;
    float t2 = fabsf(I[5][CI] - J[5][CJ]) + 1e-8f;
    PairP r;
    r.ps = fexp2(-0.72134752044448169f * sO) *
           (fexp2(0.8f * flog2(t0)) + fexp2(0.8f * flog2(t1)) + fexp2(0.8f * flog2(t2)));
    r.sq = wsd * fmaf(t0, t0, fmaf(t1, t1, t2 * t2));
    return r;
}

__device__ __forceinline__ void load_row(float R[6][4], const float* const pb[6],
                                         int row, int cm1, int c, int cp1, int cp2)
{
    const int rb = (row > 511 ? 1022 - row : row) << 9;
    #pragma unroll
    for (int p = 0; p < 6; ++p) {
        const float* g = pb[p] + rb;
        R[p][0] = g[cm1]; R[p][1] = g[c]; R[p][2] = g[cp1]; R[p][3] = g[cp2];
    }
}

__device__ __forceinline__ float combine(
    const PairP& pE, const PairP& pS, const PairP& pSE, const PairP& pSW,
    float mi, float mE, float mS, float mSE, float mSW,
    int h, int w, bool border)
{
    float a = fmaf(mi, 3e-16f - 1.1943215e-6f, 1.1943215e-6f);  // center offset
    if (!border) {
        a += (2.f - mi - mE ) * pE.ps  + (mi + mE ) * pE.sq;
        a += (2.f - mi - mS ) * pS.ps  + (mi + mS ) * pS.sq;
        a += (2.f - mi - mSE) * pSE.ps + (mi + mSE) * pSE.sq;
        a += (2.f - mi - mSW) * pSW.ps + (mi + mSW) * pSW.sq;
    } else {
        float aE = (w == 0)   ? 2.f : 1.f, bE = (w == 510) ? 2.f : 1.f;
        float aS = (h == 0)   ? 2.f : 1.f, bS = (h == 510) ? 2.f : 1.f;
        float aW = (w == 511) ? 2.f : 1.f, bW = (w == 1)   ? 2.f : 1.f;
        bool  vE = (w <= 510), vS = (h <= 510);
        bool  vD = vS && vE,   vW = vS && (w >= 1);
        float cEf = vE ? aE : 0.f,      cEb = vE ? bE : 0.f;
        float cSf = vS ? aS : 0.f,      cSb = vS ? bS : 0.f;
        float cDf = vD ? aS * aE : 0.f, cDb = vD ? bS * bE : 0.f;
        float cWf = vW ? aS * aW : 0.f, cWb = vW ? bS * bW : 0.f;
        a += (fmaf(cEf, -mi, cEf) + fmaf(cEb, -mE,  cEb)) * pE.ps  + fmaf(cEf, mi, cEb * mE ) * pE.sq;
        a += (fmaf(cSf, -mi, cSf) + fmaf(cSb, -mS,  cSb)) * pS.ps  + fmaf(cSf, mi, cSb * mS ) * pS.sq;
        a += (fmaf(cDf, -mi, cDf) + fmaf(cDb, -mSE, cDb)) * pSE.ps + fmaf(cDf, mi, cDb * mSE) * pSE.sq;
        a += (fmaf(cWf, -mi, cWf) + fmaf(cWb, -mSW, cWb)) * pSW.ps + fmaf(cWf, mi, cWb * mSW) * pSW.sq;
    }
    return a;
}

// step S: pixel row h0+S from B_(row S), C_(row S+1); N_ <- row S+2.
// mask regs: (miA,miE)=row S @ {c,c+1}; (ml,m0,mp)=row S+1 @ {c-1,c,c+1};
// prefetch row S+2 masks into (nl,n0,np).
#define KSTEP(B_, C_, N_, S_, DOLOAD_)                                          \
    {                                                                           \
        float nl = 0.f, n0 = 0.f, np = 0.f;                                     \
        if (DOLOAD_) {                                                          \
            load_row(N_, pb, h0 + (S_) + 2, cm1, c, cp1, cp2);                  \
            int rr = h0 + (S_) + 2; rr = rr > 511 ? 511 : rr;                   \
            const unsigned char* mr = mk + (rr << 9);                           \
            nl = (float)mr[cm1b]; n0 = (float)mr[c]; np = (float)mr[cp1b];      \
        }                                                                       \
        PairP pE  = pp<1, 2>(B_, B_, WS1);                                      \
        PairP pS  = pp<1, 1>(B_, C_, WS1);                                      \
        PairP pSE = pp<1, 2>(B_, C_, WS2);                                      \
        PairP pSW = pp<1, 0>(B_, C_, WS2);                                      \
        acc += combine(pE, pS, pSE, pSW, miA, miE, m0, mp, ml,                  \
                       h0 + (S_), c, wborder);                                  \
        miA = m0; miE = mp; ml = nl; m0 = n0; mp = np;                          \
    }

__global__ __launch_bounds__(256) void loss_kernel(
    const float* __restrict__ orig, const float* __restrict__ smo,
    const unsigned char* __restrict__ mask, float* __restrict__ out)
{
    const int tid  = threadIdx.x;
    const int bid  = blockIdx.x;        // 8 imgs * 64 bands(8-row) * 2 halves
    const int b    = bid >> 7;
    const int rem  = bid & 127;
    const int band = rem >> 1;
    const int half = rem & 1;
    const int h0   = band << 3;
    const int c    = (half << 8) | tid;

    const int cm1 = (c == 0)   ? 1   : c - 1;          // value reflect
    const int cp1 = (c == 511) ? 510 : c + 1;
    const int cp2 = (c >= 510) ? 1022 - (c + 2) : c + 2;
    const int cm1b = (c == 0)   ? 0   : c - 1;         // mask clamp (weight 0)
    const int cp1b = (c == 511) ? 511 : c + 1;

    const int wc = (half << 8) | (tid & 192);
    const bool wborder = (band == 0) | (band == 63) | (wc == 0) | (wc == 448);

    const float* pb[6];
    #pragma unroll
    for (int p = 0; p < 3; ++p) {
        pb[p]     = orig + ((b * 3 + p) << 18);
        pb[p + 3] = smo  + ((b * 3 + p) << 18);
    }
    const unsigned char* mk = mask + (b << 18);

    float D0[6][4], D1[6][4], D2[6][4];
    float acc = 0.f;

    // prologue: rows h0, h0+1; masks row h0 (own) + row h0+1 (below)
    load_row(D0, pb, h0,     cm1, c, cp1, cp2);
    load_row(D1, pb, h0 + 1, cm1, c, cp1, cp2);
    const unsigned char* mr0 = mk + (h0 << 9);
    const unsigned char* mr1 = mk + ((h0 + 1) << 9);
    float miA = (float)mr0[c],    miE = (float)mr0[cp1b];
    float ml  = (float)mr1[cm1b], m0  = (float)mr1[c], mp = (float)mr1[cp1b];

    KSTEP(D0, D1, D2, 0, 1)
    KSTEP(D1, D2, D0, 1, 1)
    KSTEP(D2, D0, D1, 2, 1)
    KSTEP(D0, D1, D2, 3, 1)
    KSTEP(D1, D2, D0, 4, 1)
    KSTEP(D2, D0, D1, 5, 1)
    KSTEP(D0, D1, D2, 6, 1)
    KSTEP(D1, D2, D0, 7, 0)

    acc *= (1.0f / 56623104.0f);        // mean over 8*9*3*512*512

    #pragma unroll
    for (int o = 32; o > 0; o >>= 1)
        acc += __shfl_down(acc, o, 64);

    __shared__ float wsum[4];
    const int lane = tid & 63;
    const int wid  = tid >> 6;
    if (lane == 0) wsum[wid] = acc;
    __syncthreads();
    if (tid == 0)
        atomicAdd(out, wsum[0] + wsum[1] + wsum[2] + wsum[3]);
}

extern "C" void kernel_launch(void* const* d_in, const int* in_sizes, int n_in,
                              void* d_out, int out_size, void* d_ws, size_t ws_size,
                              hipStream_t stream) {
    const float* orig = (const float*)d_in[0];
    const float* smo  = (const float*)d_in[1];
    float* out = (float*)d_out;
    unsigned char* mask = (unsigned char*)d_ws;     // 2 MB of workspace

    (void)hipMemsetAsync(out, 0, sizeof(float), stream);
    mask_kernel<<<2048, 256, 0, stream>>>(orig, smo, mask);
    loss_kernel<<<1024, 256, 0, stream>>>(orig, smo, mask, out);
}

// Round 19
// 31.479 us; speedup vs baseline: 1.3606x; 1.3606x over previous
//
#include <hip/hip_runtime.h>

__device__ __forceinline__ float fexp2(float x) { return __builtin_amdgcn_exp2f(x); }
__device__ __forceinline__ float flog2(float x) { return __builtin_amdgcn_logf(x); }

#define WS1 0.60653065971263342f   // exp(-0.5)
#define WS2 0.36787944117144233f   // exp(-1)

struct PairP { float ps, sq; };    // ps = wr*sum(t^0.8) ; sq = wsd*sum(t^2)

// mask-independent pair partials between I[.][CI] and J[.][CJ]
template<int CI, int CJ>
__device__ __forceinline__ PairP pp(const float (&I)[6][4], const float (&J)[6][4], float wsd)
{
    float d0 = I[0][CI] - J[0][CJ], d1 = I[1][CI] - J[1][CJ], d2 = I[2][CI] - J[2][CJ];
    float sO = fmaf(d0, d0, fmaf(d1, d1, d2 * d2));
    float t0 = fabsf(I[3][CI] - J[3][CJ]) + 1e-8f;
    float t1 = fabsf(I[4][CI] - J[4][CJ]) + 1e-8f;
    float t2 = fabsf(I[5][CI] - J[5][CJ]) + 1e-8f;
    PairP r;
    r.ps = fexp2(-0.72134752044448169f * sO) *
           (fexp2(0.8f * flog2(t0)) + fexp2(0.8f * flog2(t1)) + fexp2(0.8f * flog2(t2)));
    r.sq = wsd * fmaf(t0, t0, fmaf(t1, t1, t2 * t2));
    return r;
}

// load one image row: 4-col window (cm1, c, cp1, cp2 pre-reflected) x 6 planes
__device__ __forceinline__ void load_row(float R[6][4], const float* const pb[6],
                                         int row, int cm1, int c, int cp1, int cp2)
{
    const int rb = (row > 511 ? 1022 - row : row) << 9;
    #pragma unroll
    for (int p = 0; p < 6; ++p) {
        const float* g = pb[p] + rb;
        R[p][0] = g[cm1]; R[p][1] = g[c]; R[p][2] = g[cp1]; R[p][3] = g[cp2];
    }
}

// masks of X_'s row at window cols 0..2 (= c-1, c, c+1), using Y_ = row below
__device__ __forceinline__ void mask3(float M[3], const float X_[6][4], const float Y_[6][4])
{
    #pragma unroll
    for (int j = 0; j < 3; ++j) {
        float eo = 0.f, es = 0.f;
        #pragma unroll
        for (int p = 0; p < 3; ++p) {
            float a = X_[p][j];
            float d1 = a - Y_[p][j], d2 = a - X_[p][j + 1];
            eo += d1 * d1 + d2 * d2;
            float s = X_[p + 3][j];
            float f1 = s - Y_[p + 3][j], f2 = s - X_[p + 3][j + 1];
            es += f1 * f1 + f2 * f2;
        }
        M[j] = (eo < 1.f && es - eo > 1.f) ? 1.f : 0.f;
    }
}

// combine partials with masks (+ reflection multiplicities on border waves)
__device__ __forceinline__ float combine(
    const PairP& pE, const PairP& pS, const PairP& pSE, const PairP& pSW,
    float mi, float mE, float mS, float mSE, float mSW,
    int h, int w, bool border)
{
    float a = fmaf(mi, 3e-16f - 1.1943215e-6f, 1.1943215e-6f);  // center offset
    if (!border) {
        a += (2.f - mi - mE ) * pE.ps  + (mi + mE ) * pE.sq;
        a += (2.f - mi - mS ) * pS.ps  + (mi + mS ) * pS.sq;
        a += (2.f - mi - mSE) * pSE.ps + (mi + mSE) * pSE.sq;
        a += (2.f - mi - mSW) * pSW.ps + (mi + mSW) * pSW.sq;
    } else {
        float aE = (w == 0)   ? 2.f : 1.f, bE = (w == 510) ? 2.f : 1.f;
        float aS = (h == 0)   ? 2.f : 1.f, bS = (h == 510) ? 2.f : 1.f;
        float aW = (w == 511) ? 2.f : 1.f, bW = (w == 1)   ? 2.f : 1.f;
        bool  vE = (w <= 510), vS = (h <= 510);
        bool  vD = vS && vE,   vW = vS && (w >= 1);
        float cEf = vE ? aE : 0.f,      cEb = vE ? bE : 0.f;
        float cSf = vS ? aS : 0.f,      cSb = vS ? bS : 0.f;
        float cDf = vD ? aS * aE : 0.f, cDb = vD ? bS * bE : 0.f;
        float cWf = vW ? aS * aW : 0.f, cWb = vW ? bS * bW : 0.f;
        a += (fmaf(cEf, -mi, cEf) + fmaf(cEb, -mE,  cEb)) * pE.ps  + fmaf(cEf, mi, cEb * mE ) * pE.sq;
        a += (fmaf(cSf, -mi, cSf) + fmaf(cSb, -mS,  cSb)) * pS.ps  + fmaf(cSf, mi, cSb * mS ) * pS.sq;
        a += (fmaf(cDf, -mi, cDf) + fmaf(cDb, -mSE, cDb)) * pSE.ps + fmaf(cDf, mi, cDb * mSE) * pSE.sq;
        a += (fmaf(cWf, -mi, cWf) + fmaf(cWb, -mSW, cWb)) * pSW.ps + fmaf(cWf, mi, cWb * mSW) * pSW.sq;
    }
    return a;
}

// march step for pixel row h0+S: B_=row h0+S, C_=+1, N1_=+2 (loaded last step),
// NL_ receives row h0+S+3 (issued now, consumed next step by mask3)
#define MSTEP(B_, C_, N1_, NL_, S_)                                             \
    {                                                                           \
        load_row(NL_, pb, h0 + (S_) + 3, cm1, c, cp1, cp2);                     \
        PairP pE  = pp<1, 2>(B_, B_, WS1);                                      \
        PairP pS  = pp<1, 1>(B_, C_, WS1);                                      \
        PairP pSE = pp<1, 2>(B_, C_, WS2);                                      \
        PairP pSW = pp<1, 0>(B_, C_, WS2);                                      \
        float mN[3]; mask3(mN, C_, N1_);                                        \
        acc += combine(pE, pS, pSE, pSW, mB[1], mB[2], mN[1], mN[2], mN[0],     \
                       h0 + (S_), c, wborder);                                  \
        mB[0] = mN[0]; mB[1] = mN[1]; mB[2] = mN[2];                            \
    }

__global__ __launch_bounds__(256) void smooth_loss_kernel(
    const float* __restrict__ orig, const float* __restrict__ smo,
    float* __restrict__ out)
{
    const int tid  = threadIdx.x;
    const int bid  = blockIdx.x;        // 8 imgs * 32 bands * 2 col-halves
    const int b    = bid >> 6;
    const int rem  = bid & 63;
    const int band = rem >> 1;
    const int half = rem & 1;
    const int h0   = band << 4;         // 16-row segment
    const int c    = (half << 8) | tid; // own column

    // pre-reflected window col indices (c-1, c, c+1, c+2)
    const int cm1 = (c == 0)   ? 1   : c - 1;
    const int cp1 = (c == 511) ? 510 : c + 1;
    const int cp2 = (c >= 510) ? 1022 - (c + 2) : c + 2;

    const int wc = (half << 8) | (tid & 192);   // wave's first col
    const bool wborder = (band == 0) | (band == 31) | (wc == 0) | (wc == 448);

    const float* pb[6];
    #pragma unroll
    for (int p = 0; p < 3; ++p) {
        pb[p]     = orig + ((b * 3 + p) << 18);
        pb[p + 3] = smo  + ((b * 3 + p) << 18);
    }

    float D0[6][4], D1[6][4], D2[6][4], D3[6][4];
    float mB[3];
    float acc = 0.f;

    // prologue: rows h0 .. h0+2 in flight, mask of row h0
    load_row(D0, pb, h0,     cm1, c, cp1, cp2);
    load_row(D1, pb, h0 + 1, cm1, c, cp1, cp2);
    load_row(D2, pb, h0 + 2, cm1, c, cp1, cp2);
    mask3(mB, D0, D1);

    // rolled march: 4 iterations x 4 steps; buffer rotation period == body length.
    // Final step's prefetch (row h0+18 <= 514, reflected to <=508) is dead but safe.
    #pragma unroll 1
    for (int g = 0; g < 4; ++g) {
        const int s0 = g << 2;
        MSTEP(D0, D1, D2, D3, s0 + 0)
        MSTEP(D1, D2, D3, D0, s0 + 1)
        MSTEP(D2, D3, D0, D1, s0 + 2)
        MSTEP(D3, D0, D1, D2, s0 + 3)
    }

    acc *= (1.0f / 56623104.0f);        // mean over 8*9*3*512*512

    #pragma unroll
    for (int o = 32; o > 0; o >>= 1)
        acc += __shfl_down(acc, o, 64);

    __shared__ float wsum[4];
    const int lane = tid & 63;
    const int wid  = tid >> 6;
    if (lane == 0) wsum[wid] = acc;
    __syncthreads();
    if (tid == 0)
        atomicAdd(out, wsum[0] + wsum[1] + wsum[2] + wsum[3]);
}

extern "C" void kernel_launch(void* const* d_in, const int* in_sizes, int n_in,
                              void* d_out, int out_size, void* d_ws, size_t ws_size,
                              hipStream_t stream) {
    const float* orig = (const float*)d_in[0];
    const float* smo  = (const float*)d_in[1];
    float* out = (float*)d_out;

    (void)hipMemsetAsync(out, 0, sizeof(float), stream);
    smooth_loss_kernel<<<512, 256, 0, stream>>>(orig, smo, out);
}